// Round 13
// baseline (320.434 us; speedup 1.0000x reference)
//
#include <hip/hip_runtime.h>
#include <math.h>

#define H 768
#define L 256
#define NB 4
#define NL 13
#define MT_TILES 16
#define NT_TILES 24
#define N_TICKETS (MT_TILES * NT_TILES)   // 384

typedef _Float16 h2 __attribute__((ext_vector_type(2)));
typedef _Float16 h4 __attribute__((ext_vector_type(4)));
typedef _Float16 half8 __attribute__((ext_vector_type(8)));
typedef float f32x4 __attribute__((ext_vector_type(4)));

// Packed-fp16 GELU (h2 ext-vector -> v_pk_* codegen).
__device__ inline h2 gelu_pk(h2 x) {
    const _Float16 kC = (_Float16)3.75f;
    h2 hi = {kC, kC}, lo = {(_Float16)-3.75f, (_Float16)-3.75f};
    h2 xc = __builtin_elementwise_min(__builtin_elementwise_max(x, lo), hi);
    h2 u = xc * xc;
    const _Float16 kE = (_Float16)0.125f;
    h2 ve = {kE, kE};
    h2 v = u * ve;
    const _Float16 d4v = (_Float16)0.0832840f,  d3v = (_Float16)-0.4335206f;
    const _Float16 d2v = (_Float16)0.8960128f,  d1v = (_Float16)-0.9876456f;
    const _Float16 d0v = (_Float16)0.7946463f;
    h2 d4 = {d4v, d4v}, d3 = {d3v, d3v}, d2 = {d2v, d2v}, d1 = {d1v, d1v}, d0 = {d0v, d0v};
    h2 p = v * (v * (v * (v * d4 + d3) + d2) + d1) + d0;
    h2 t = xc * p;
    const _Float16 kH = (_Float16)0.5f;
    h2 halfv = {kH, kH};
    h2 hx = x * halfv;
    return hx * t + hx;
}

// ---------------- Single-launch producer/consumer kernel ---------------------
// grid 1024 x 256. Phase 1: ticket-queue GEMM tiles (384 tickets; any resident
// subset drains the queue -> deadlock-free). Per-tile release: threadfence +
// flags[mt*2+half]++. Phase 2: every block builds W2 frags in LDS, acquire-polls
// the two flags its span slice needs, then runs the R12 span.
__global__ __launch_bounds__(256, 3) void mono_kernel(
    const float* __restrict__ X, const float* __restrict__ W1,
    const float* __restrict__ b1, const float* __restrict__ W2,
    const float* __restrict__ b2,
    _Float16* __restrict__ Pxs2, _Float16* __restrict__ Pxe,
    int* __restrict__ ctrl, float* __restrict__ out)
{
    __shared__ _Float16 As[64][72];              // 9.2 KB
    __shared__ _Float16 Bs[64][72];              // 9.2 KB
    __shared__ _Float16 w2f[24 * 64 * 8];        // 24 KB
    __shared__ unsigned int xsf[4 * H / 2];      // 6 KB
    __shared__ int s_ticket;

    const int tid = threadIdx.x;
    const int w = tid >> 6, lane = tid & 63;
    const int ln = lane & 15, quad = lane >> 4;
    int* ticket = ctrl;
    int* flags  = ctrl + 1;                      // 32 counters (16 mt x 2 halves)

    // ================= Phase 1: GEMM tile ticket loop =================
    for (;;) {
        __syncthreads();
        if (tid == 0) s_ticket = atomicAdd(ticket, 1);
        __syncthreads();
        const int t = s_ticket;
        if (t >= N_TICKETS) break;

        const int mtile = t / NT_TILES;          // [0,16)
        const int ntile = t % NT_TILES;          // [0,24)
        const int m0 = mtile * 64;
        const int n0g = ntile * 64;              // n' in [0,1536)
        const bool isE = (n0g >= H);
        const float* Wb = W1 + (isE ? (size_t)H * H : 0);
        const int c0 = isE ? (n0g - H) : n0g;

        const int ar = tid >> 4;
        const int ac = (tid & 15) * 4;
        const int bc = (tid & 15) * 4;

        f32x4 acc[2][2] = {};
        for (int kr = 0; kr < H / 64; ++kr) {
            const int k0 = kr * 64;
            #pragma unroll
            for (int r = 0; r < 4; ++r) {
                int arow = r * 16 + ar;
                float4 f = *(const float4*)&X[(size_t)(m0 + arow) * H + k0 + ac];
                h4 o = { (_Float16)f.x, (_Float16)f.y, (_Float16)f.z, (_Float16)f.w };
                *(h4*)&As[arow][ac] = o;
            }
            #pragma unroll
            for (int r = 0; r < 2; ++r) {
                int kpl = r * 16 + (tid >> 4);
                const float* wr = &Wb[(size_t)(k0 + 2 * kpl) * H + c0 + bc];
                float4 fa = *(const float4*)wr;
                float4 fb = *(const float4*)(wr + H);
                h2 p0 = {(_Float16)fa.x, (_Float16)fb.x};
                h2 p1 = {(_Float16)fa.y, (_Float16)fb.y};
                h2 p2 = {(_Float16)fa.z, (_Float16)fb.z};
                h2 p3 = {(_Float16)fa.w, (_Float16)fb.w};
                *(h2*)&Bs[bc + 0][2 * kpl] = p0;
                *(h2*)&Bs[bc + 1][2 * kpl] = p1;
                *(h2*)&Bs[bc + 2][2 * kpl] = p2;
                *(h2*)&Bs[bc + 3][2 * kpl] = p3;
            }
            __syncthreads();
            #pragma unroll
            for (int sub = 0; sub < 2; ++sub) {
                const int ko = sub * 32 + quad * 8;
                half8 a0 = *(const half8*)&As[(w & 1) * 32 + ln][ko];
                half8 a1 = *(const half8*)&As[(w & 1) * 32 + 16 + ln][ko];
                half8 b0 = *(const half8*)&Bs[(w >> 1) * 32 + ln][ko];
                half8 b1f = *(const half8*)&Bs[(w >> 1) * 32 + 16 + ln][ko];
                acc[0][0] = __builtin_amdgcn_mfma_f32_16x16x32_f16(a0, b0, acc[0][0], 0, 0, 0);
                acc[0][1] = __builtin_amdgcn_mfma_f32_16x16x32_f16(a0, b1f, acc[0][1], 0, 0, 0);
                acc[1][0] = __builtin_amdgcn_mfma_f32_16x16x32_f16(a1, b0, acc[1][0], 0, 0, 0);
                acc[1][1] = __builtin_amdgcn_mfma_f32_16x16x32_f16(a1, b1f, acc[1][1], 0, 0, 0);
            }
            __syncthreads();
        }

        const int mb = m0 + (w & 1) * 32;
        const int nb = (w >> 1) * 32;
        if (!isE) {
            float bv[2] = { b1[n0g + nb + ln], b1[n0g + nb + 16 + ln] };
            #pragma unroll
            for (int mt = 0; mt < 2; ++mt)
                #pragma unroll
                for (int nt = 0; nt < 2; ++nt) {
                    int n = n0g + nb + nt * 16 + ln;
                    #pragma unroll
                    for (int r = 0; r < 4; ++r) {
                        int m = mb + mt * 16 + quad * 4 + r;
                        Pxs2[(size_t)m * H + n] = (_Float16)(acc[mt][nt][r] + bv[nt]);
                    }
                }
        } else {
            #pragma unroll
            for (int mt = 0; mt < 2; ++mt)
                #pragma unroll
                for (int nt = 0; nt < 2; ++nt) {
                    int n = c0 + nb + nt * 16 + ln;
                    #pragma unroll
                    for (int r = 0; r < 4; ++r) {
                        int m = mb + mt * 16 + quad * 4 + r;
                        Pxe[(size_t)m * H + n] = (_Float16)acc[mt][nt][r];
                    }
                }
        }
        __threadfence();                         // release: stores -> device scope
        __syncthreads();                         // all waves fenced
        if (tid == 0) atomicAdd(&flags[mtile * 2 + (isE ? 1 : 0)], 1);
    }

    // ================= Phase 2: span =================
    // Build W2 B-fragments in LDS (w2f[kb][lane][8]).
    #pragma unroll 4
    for (int r = 0; r < 48; ++r) {
        int idx = r * 256 + tid;                 // < 12288
        int u = idx & 7;
        int l = (idx >> 3) & 63;
        int kb = idx >> 9;
        int k = kb * 32 + ((l >> 4) << 3) + u;
        int n = l & 15;
        float v = (n < NL) ? W2[(size_t)k * NL + n] : 0.f;
        w2f[idx] = (_Float16)v;
    }

    const int ip = blockIdx.x >> 2;              // 0..255
    const int jq = blockIdx.x & 3;
    const int bi0 = ip * 4;                      // b*L + i quad start
    const int b = bi0 >> 8;
    const int mt_i = ip >> 4;                    // m-tile of xs rows
    const int mt_j = b * 4 + jq;                 // m-tile of xe rows

    // acquire-poll the two producer flags (12 n-tiles each)
    while (__hip_atomic_load(&flags[mt_i * 2 + 0], __ATOMIC_RELAXED, __HIP_MEMORY_SCOPE_AGENT) < 12 ||
           __hip_atomic_load(&flags[mt_j * 2 + 1], __ATOMIC_RELAXED, __HIP_MEMORY_SCOPE_AGENT) < 12) {
        __builtin_amdgcn_s_sleep(16);
    }
    __threadfence();                             // acquire

    const unsigned int* xsrc = (const unsigned int*)(Pxs2 + (size_t)bi0 * H);
    #pragma unroll
    for (int t = 0; t < 6; ++t) xsf[t * 256 + tid] = xsrc[t * 256 + tid];

    const int n = ln;
    const int j_load = jq * 64 + w * 16 + n;     // A-frag row m = lane&15
    const _Float16* xerow = Pxe + (size_t)(b * L + j_load) * H + quad * 8;

    f32x4 acc[4] = {};
    __syncthreads();

    for (int kb = 0; kb < H / 32; ++kb) {
        half8 bfrag = *(const half8*)&w2f[((size_t)kb * 64 + lane) * 8];
        uint4 xev = *(const uint4*)(xerow + kb * 32);
        h2 xep[4] = { __builtin_bit_cast(h2, xev.x), __builtin_bit_cast(h2, xev.y),
                      __builtin_bit_cast(h2, xev.z), __builtin_bit_cast(h2, xev.w) };
        const int xo = kb * 16 + quad * 4;

        #pragma unroll
        for (int i01 = 0; i01 < 4; ++i01) {
            uint4 xsd = *(const uint4*)&xsf[i01 * (H / 2) + xo];
            h2 xsp[4] = { __builtin_bit_cast(h2, xsd.x), __builtin_bit_cast(h2, xsd.y),
                          __builtin_bit_cast(h2, xsd.z), __builtin_bit_cast(h2, xsd.w) };
            unsigned int pk[4];
            #pragma unroll
            for (int p = 0; p < 4; ++p) {
                h2 g = gelu_pk(xsp[p] + xep[p]);
                pk[p] = __builtin_bit_cast(unsigned int, g);
            }
            uint4 pk4 = {pk[0], pk[1], pk[2], pk[3]};
            half8 afrag = __builtin_bit_cast(half8, pk4);
            acc[i01] = __builtin_amdgcn_mfma_f32_16x16x32_f16(afrag, bfrag, acc[i01], 0, 0, 0);
        }
    }

    if (n < NL) {
        float b2v = b2[n];
        #pragma unroll
        for (int i01 = 0; i01 < 4; ++i01)
            #pragma unroll
            for (int r = 0; r < 4; ++r) {
                int j = jq * 64 + w * 16 + quad * 4 + r;
                out[((size_t)(bi0 + i01) * L + j) * NL + n] = acc[i01][r] + b2v;
            }
    }
}

// ---------------- Launch ------------------------------------------------------
extern "C" void kernel_launch(void* const* d_in, const int* in_sizes, int n_in,
                              void* d_out, int out_size, void* d_ws, size_t ws_size,
                              hipStream_t stream)
{
    (void)in_sizes; (void)n_in; (void)out_size; (void)ws_size;
    const float* X  = (const float*)d_in[0];
    const float* W1 = (const float*)d_in[1];
    const float* b1 = (const float*)d_in[2];
    const float* W2 = (const float*)d_in[3];
    const float* b2 = (const float*)d_in[4];
    float* out = (float*)d_out;

    char* ws = (char*)d_ws;
    _Float16* Pxs2 = (_Float16*)ws;                            // 1.5 MB
    _Float16* Pxe  = Pxs2 + (size_t)NB * L * H;                // 1.5 MB
    int* ctrl      = (int*)(Pxe + (size_t)NB * L * H);         // ticket + 32 flags

    hipMemsetAsync(ctrl, 0, 256, stream);
    mono_kernel<<<1024, 256, 0, stream>>>(X, W1, b1, W2, b2, Pxs2, Pxe, ctrl, out);
}

// Round 14
// 122.231 us; speedup vs baseline: 2.6215x; 2.6215x over previous
//
#include <hip/hip_runtime.h>
#include <math.h>

#define H 768
#define L 256
#define NB 4
#define NL 13

typedef _Float16 h2 __attribute__((ext_vector_type(2)));
typedef _Float16 h4 __attribute__((ext_vector_type(4)));
typedef _Float16 half8 __attribute__((ext_vector_type(8)));
typedef float f32x4 __attribute__((ext_vector_type(4)));

// Packed-fp16 GELU, u-space poly (11 pk ops incl. caller's input add).
// erf(x/sqrt2) ~= xc*P(u), u=xc*xc, xc=clamp(x,+-3.75).
// d4 (2.03e-5) is an f16 subnormal: exactly representable to 0.03%, full-rate.
__device__ inline h2 gelu_pk(h2 x) {
    const _Float16 kC = (_Float16)3.75f;
    h2 hi = {kC, kC}, lo = {(_Float16)-3.75f, (_Float16)-3.75f};
    h2 xc = __builtin_elementwise_min(__builtin_elementwise_max(x, lo), hi);
    h2 u = xc * xc;
    const _Float16 d4v = (_Float16)2.0333e-5f,  d3v = (_Float16)-0.00084672f;
    const _Float16 d2v = (_Float16)0.0140002f,  d1v = (_Float16)-0.1234557f;
    const _Float16 d0v = (_Float16)0.7946463f;
    h2 d4 = {d4v, d4v}, d3 = {d3v, d3v}, d2 = {d2v, d2v}, d1 = {d1v, d1v}, d0 = {d0v, d0v};
    h2 p = u * (u * (u * (u * d4 + d3) + d2) + d1) + d0;   // v_pk_fma_f16 chain
    h2 t = xc * p;
    h2 w = x * t + x;                       // x*(1+t) via pk fma
    const _Float16 kH = (_Float16)0.5f;
    h2 halfv = {kH, kH};
    return w * halfv;
}

// ---------------- Kernel 1: fused prep + classic LDS-staged GEMM (R12) -------
__global__ __launch_bounds__(256) void gemm_fused(
    const float* __restrict__ X, const float* __restrict__ W1,
    const float* __restrict__ b1, const float* __restrict__ W2,
    _Float16* __restrict__ Pxs2, _Float16* __restrict__ Pxe,
    _Float16* __restrict__ Bfrag2)
{
    const int tid = threadIdx.x;

    if (blockIdx.y == 24) {
        int base = blockIdx.x * 768 + tid;
        #pragma unroll
        for (int r = 0; r < 3; ++r) {
            int idx = base + r * 256;            // < 12288
            int u = idx & 7;
            int lane = (idx >> 3) & 63;
            int kb = idx >> 9;
            int k = kb * 32 + ((lane >> 4) << 3) + u;
            int n = lane & 15;
            float v = (n < NL) ? W2[(size_t)k * NL + n] : 0.f;
            Bfrag2[idx] = (_Float16)v;
        }
        return;
    }

    __shared__ _Float16 As[64][72];              // [m][k-local]
    __shared__ _Float16 Bs[64][72];              // [n][k-local]
    const int w = tid >> 6, lane = tid & 63;
    const int ln = lane & 15, quad = lane >> 4;
    const int m0 = blockIdx.x * 64;
    const int n0g = blockIdx.y * 64;             // n' in [0,1536)
    const bool isE = (n0g >= H);
    const float* Wb = W1 + (isE ? (size_t)H * H : 0);
    const int c0 = isE ? (n0g - H) : n0g;

    const int ar = tid >> 4;
    const int ac = (tid & 15) * 4;
    const int bc = (tid & 15) * 4;

    f32x4 acc[2][2] = {};
    for (int kr = 0; kr < H / 64; ++kr) {
        const int k0 = kr * 64;
        #pragma unroll
        for (int r = 0; r < 4; ++r) {
            int arow = r * 16 + ar;
            float4 f = *(const float4*)&X[(size_t)(m0 + arow) * H + k0 + ac];
            h4 o = { (_Float16)f.x, (_Float16)f.y, (_Float16)f.z, (_Float16)f.w };
            *(h4*)&As[arow][ac] = o;
        }
        #pragma unroll
        for (int r = 0; r < 2; ++r) {
            int kpl = r * 16 + (tid >> 4);
            const float* wr = &Wb[(size_t)(k0 + 2 * kpl) * H + c0 + bc];
            float4 fa = *(const float4*)wr;
            float4 fb = *(const float4*)(wr + H);
            h2 p0 = {(_Float16)fa.x, (_Float16)fb.x};
            h2 p1 = {(_Float16)fa.y, (_Float16)fb.y};
            h2 p2 = {(_Float16)fa.z, (_Float16)fb.z};
            h2 p3 = {(_Float16)fa.w, (_Float16)fb.w};
            *(h2*)&Bs[bc + 0][2 * kpl] = p0;
            *(h2*)&Bs[bc + 1][2 * kpl] = p1;
            *(h2*)&Bs[bc + 2][2 * kpl] = p2;
            *(h2*)&Bs[bc + 3][2 * kpl] = p3;
        }
        __syncthreads();
        #pragma unroll
        for (int sub = 0; sub < 2; ++sub) {
            const int ko = sub * 32 + quad * 8;
            half8 a0 = *(const half8*)&As[(w & 1) * 32 + ln][ko];
            half8 a1 = *(const half8*)&As[(w & 1) * 32 + 16 + ln][ko];
            half8 b0 = *(const half8*)&Bs[(w >> 1) * 32 + ln][ko];
            half8 b1f = *(const half8*)&Bs[(w >> 1) * 32 + 16 + ln][ko];
            acc[0][0] = __builtin_amdgcn_mfma_f32_16x16x32_f16(a0, b0, acc[0][0], 0, 0, 0);
            acc[0][1] = __builtin_amdgcn_mfma_f32_16x16x32_f16(a0, b1f, acc[0][1], 0, 0, 0);
            acc[1][0] = __builtin_amdgcn_mfma_f32_16x16x32_f16(a1, b0, acc[1][0], 0, 0, 0);
            acc[1][1] = __builtin_amdgcn_mfma_f32_16x16x32_f16(a1, b1f, acc[1][1], 0, 0, 0);
        }
        __syncthreads();
    }

    const int mb = m0 + (w & 1) * 32;
    const int nb = (w >> 1) * 32;
    if (!isE) {
        float bv[2] = { b1[n0g + nb + ln], b1[n0g + nb + 16 + ln] };
        #pragma unroll
        for (int mt = 0; mt < 2; ++mt)
            #pragma unroll
            for (int nt = 0; nt < 2; ++nt) {
                int n = n0g + nb + nt * 16 + ln;
                #pragma unroll
                for (int r = 0; r < 4; ++r) {
                    int m = mb + mt * 16 + quad * 4 + r;
                    Pxs2[(size_t)m * H + n] = (_Float16)(acc[mt][nt][r] + bv[nt]);
                }
            }
    } else {
        #pragma unroll
        for (int mt = 0; mt < 2; ++mt)
            #pragma unroll
            for (int nt = 0; nt < 2; ++nt) {
                int n = c0 + nb + nt * 16 + ln;
                #pragma unroll
                for (int r = 0; r < 4; ++r) {
                    int m = mb + mt * 16 + quad * 4 + r;
                    Pxe[(size_t)m * H + n] = (_Float16)acc[mt][nt][r];
                }
            }
    }
}

// ---------------- Kernel 2: span v5 ------------------------------------------
// grid 1024: block = (iquad, jq). Each wave: 16 j x 4 i sharing xe/bfrag loads.
// Distance-2 xe prefetch (register rotation, unroll 3) hides the per-kb L2 hit.
__global__ __launch_bounds__(256, 3) void span_mfma_kernel(
    const _Float16* __restrict__ Pxs2, const _Float16* __restrict__ Pxe,
    const _Float16* __restrict__ Bfrag2, const float* __restrict__ b2,
    float* __restrict__ out)
{
    __shared__ unsigned int xsf[4 * H / 2];   // four i-rows of fp16 pairs (6 KB)
    const int ip = blockIdx.x >> 2;           // 0..255
    const int jq = blockIdx.x & 3;
    const int bi0 = ip * 4;                   // b*L + i (quad start; same b)
    const int b = bi0 >> 8;
    const int tid = threadIdx.x;

    const unsigned int* xsrc = (const unsigned int*)(Pxs2 + (size_t)bi0 * H);
    #pragma unroll
    for (int t = 0; t < 6; ++t) xsf[t * 256 + tid] = xsrc[t * 256 + tid];

    const int wave = tid >> 6;
    const int lane = tid & 63;
    const int n = lane & 15;
    const int quad = lane >> 4;
    const int j_load = jq * 64 + wave * 16 + n;       // A-frag row m = lane&15

    const _Float16* xerow = Pxe + (size_t)(b * L + j_load) * H + quad * 8;
    const half8* bptr = (const half8*)(Bfrag2 + (size_t)lane * 8);

    f32x4 acc[4] = {};
    __syncthreads();

    uint4 xe0 = *(const uint4*)(xerow);               // kb
    uint4 xe1 = *(const uint4*)(xerow + 32);          // kb+1

    #pragma unroll 3
    for (int kb = 0; kb < H / 32; ++kb) {
        uint4 xecur = xe0;
        xe0 = xe1;
        if (kb < H / 32 - 2)                           // wave-uniform
            xe1 = *(const uint4*)(xerow + (kb + 2) * 32);

        half8 bfrag = bptr[kb * 64];
        h2 xep[4] = { __builtin_bit_cast(h2, xecur.x), __builtin_bit_cast(h2, xecur.y),
                      __builtin_bit_cast(h2, xecur.z), __builtin_bit_cast(h2, xecur.w) };
        const int xo = kb * 16 + quad * 4;            // uint index of lane's 8 fp16

        #pragma unroll
        for (int i01 = 0; i01 < 4; ++i01) {
            uint4 xsd = *(const uint4*)&xsf[i01 * (H / 2) + xo];
            h2 xsp[4] = { __builtin_bit_cast(h2, xsd.x), __builtin_bit_cast(h2, xsd.y),
                          __builtin_bit_cast(h2, xsd.z), __builtin_bit_cast(h2, xsd.w) };
            unsigned int pk[4];
            #pragma unroll
            for (int p = 0; p < 4; ++p) {
                h2 g = gelu_pk(xsp[p] + xep[p]);
                pk[p] = __builtin_bit_cast(unsigned int, g);
            }
            uint4 pk4 = {pk[0], pk[1], pk[2], pk[3]};
            half8 afrag = __builtin_bit_cast(half8, pk4);
            acc[i01] = __builtin_amdgcn_mfma_f32_16x16x32_f16(afrag, bfrag, acc[i01], 0, 0, 0);
        }
    }

    // C/D: col = lane&15 = label n, row = quad*4 + r = j-offset in the m-tile
    if (n < NL) {
        float b2v = b2[n];
        #pragma unroll
        for (int i01 = 0; i01 < 4; ++i01)
            #pragma unroll
            for (int r = 0; r < 4; ++r) {
                int j = jq * 64 + wave * 16 + quad * 4 + r;
                out[((size_t)(bi0 + i01) * L + j) * NL + n] = acc[i01][r] + b2v;
            }
    }
}

// ---------------- Launch ------------------------------------------------------
extern "C" void kernel_launch(void* const* d_in, const int* in_sizes, int n_in,
                              void* d_out, int out_size, void* d_ws, size_t ws_size,
                              hipStream_t stream)
{
    (void)in_sizes; (void)n_in; (void)out_size; (void)ws_size;
    const float* X  = (const float*)d_in[0];
    const float* W1 = (const float*)d_in[1];
    const float* b1 = (const float*)d_in[2];
    const float* W2 = (const float*)d_in[3];
    const float* b2 = (const float*)d_in[4];
    float* out = (float*)d_out;

    char* ws = (char*)d_ws;
    _Float16* Pxs2   = (_Float16*)ws;                          // 1.5 MB
    _Float16* Pxe    = Pxs2 + (size_t)NB * L * H;              // 1.5 MB
    _Float16* Bfrag2 = Pxe + (size_t)NB * L * H;               // 24 KB

    gemm_fused<<<dim3(16, 25), 256, 0, stream>>>(X, W1, b1, W2, Pxs2, Pxe, Bfrag2);
    span_mfma_kernel<<<NB * L, 256, 0, stream>>>(Pxs2, Pxe, Bfrag2, b2, out);
}